// Round 14
// baseline (70.450 us; speedup 1.0000x reference)
//
#include <hip/hip_runtime.h>

#define C_DIM 19
#define G_DIM 8
#define H_DIM 512
#define W_DIM 512
#define B_DIM 4
#define PLANE (H_DIM * W_DIM)
#define NPIX  (B_DIM * PLANE)
#define NT    256

__device__ __forceinline__ unsigned bf16rne(float f) {
    unsigned x = __float_as_uint(f);
    return (x + 0x7fffu + ((x >> 16) & 1u)) >> 16;
}
__device__ __forceinline__ float up_lo(unsigned u) { return __uint_as_float(u << 16); }
__device__ __forceinline__ float up_hi(unsigned u) { return __uint_as_float(u & 0xffff0000u); }

__device__ __forceinline__ void ntstore2(float* p, float f0, float f1) {
    unsigned long long v = (unsigned long long)__float_as_uint(f0) |
                           ((unsigned long long)__float_as_uint(f1) << 32);
    __builtin_nontemporal_store(v, (unsigned long long*)p);
}

// E = softmax(100*matrix over g): E4[c][0]=g0..3, E4[c][1]=g4..7.  NO sync inside.
__device__ __forceinline__ void build_E_nosync(const float* __restrict__ matrix,
                                               float4 (*E4)[2], int tid) {
    if (tid < C_DIM) {
        const int c = tid;
        float m[G_DIM];
        float mx = -1e30f;
        #pragma unroll
        for (int g = 0; g < G_DIM; ++g) {
            m[g] = 100.0f * matrix[g * C_DIM + c];
            mx = fmaxf(mx, m[g]);
        }
        float s = 0.0f;
        #pragma unroll
        for (int g = 0; g < G_DIM; ++g) { m[g] = __expf(m[g] - mx); s += m[g]; }
        const float inv = 1.0f / s;
        E4[c][0] = make_float4(m[0]*inv, m[1]*inv, m[2]*inv, m[3]*inv);
        E4[c][1] = make_float4(m[4]*inv, m[5]*inv, m[6]*inv, m[7]*inv);
    }
}

// softmax over C + encode to G for 2 px; pack 2x uint4 bf16 to LDS.
// If lg != nullptr, retain the 19 logit float2 values (row-y decode needs them).
__device__ __forceinline__ void softmax2_to_lds(const float* __restrict__ p,
                                                const float4 (*E4)[2],
                                                uint4* __restrict__ dst,
                                                float2* __restrict__ lg) {
    float eg[G_DIM][2];
    #pragma unroll
    for (int g = 0; g < G_DIM; ++g) { eg[g][0] = 0.0f; eg[g][1] = 0.0f; }
    float s0 = 0.0f, s1 = 0.0f;

    #pragma unroll
    for (int c = 0; c < C_DIM; ++c) {
        const float2 lv = *(const float2*)(p + (size_t)c * PLANE);
        if (lg) lg[c] = lv;
        const float e0 = __expf(lv.x);
        const float e1 = __expf(lv.y);
        s0 += e0; s1 += e1;
        const float4 E0 = E4[c][0];
        const float4 E1 = E4[c][1];
        eg[0][0] = fmaf(E0.x, e0, eg[0][0]);  eg[0][1] = fmaf(E0.x, e1, eg[0][1]);
        eg[1][0] = fmaf(E0.y, e0, eg[1][0]);  eg[1][1] = fmaf(E0.y, e1, eg[1][1]);
        eg[2][0] = fmaf(E0.z, e0, eg[2][0]);  eg[2][1] = fmaf(E0.z, e1, eg[2][1]);
        eg[3][0] = fmaf(E0.w, e0, eg[3][0]);  eg[3][1] = fmaf(E0.w, e1, eg[3][1]);
        eg[4][0] = fmaf(E1.x, e0, eg[4][0]);  eg[4][1] = fmaf(E1.x, e1, eg[4][1]);
        eg[5][0] = fmaf(E1.y, e0, eg[5][0]);  eg[5][1] = fmaf(E1.y, e1, eg[5][1]);
        eg[6][0] = fmaf(E1.z, e0, eg[6][0]);  eg[6][1] = fmaf(E1.z, e1, eg[6][1]);
        eg[7][0] = fmaf(E1.w, e0, eg[7][0]);  eg[7][1] = fmaf(E1.w, e1, eg[7][1]);
    }
    {
        const float inv = 1.0f / s0;
        uint4 u;
        u.x = bf16rne(eg[0][0]*inv) | (bf16rne(eg[1][0]*inv) << 16);
        u.y = bf16rne(eg[2][0]*inv) | (bf16rne(eg[3][0]*inv) << 16);
        u.z = bf16rne(eg[4][0]*inv) | (bf16rne(eg[5][0]*inv) << 16);
        u.w = bf16rne(eg[6][0]*inv) | (bf16rne(eg[7][0]*inv) << 16);
        dst[0] = u;
    }
    {
        const float inv = 1.0f / s1;
        uint4 u;
        u.x = bf16rne(eg[0][1]*inv) | (bf16rne(eg[1][1]*inv) << 16);
        u.y = bf16rne(eg[2][1]*inv) | (bf16rne(eg[3][1]*inv) << 16);
        u.z = bf16rne(eg[4][1]*inv) | (bf16rne(eg[5][1]*inv) << 16);
        u.w = bf16rne(eg[6][1]*inv) | (bf16rne(eg[7][1]*inv) << 16);
        dst[1] = u;
    }
}

// ---- fully fused: one block per image row (b, y); 2 px/thread ----
// Softmax+encode computed for rows y-1, y, y+1 (3x redundant, VALU-cheap),
// staged in LDS; then 3x3 filter + decode + subtract + nt-store.
__global__ __launch_bounds__(NT)
void gacrf_row(const float* __restrict__ F,
               const float* __restrict__ logit,
               const float* __restrict__ matrix,
               float* __restrict__ out)
{
    __shared__ float4 E4[C_DIM][2];
    __shared__ uint4  ldsQ[3][W_DIM];    // 24576 B: rows y-1, y, y+1 (bf16 x8 / px)

    const int tid = threadIdx.x;

    // XCD-chunked bijective swizzle (2048 blocks, chunk 256): y-adjacent rows
    // land on the same XCD -> shared logit rows are L2-local.
    const int bid = blockIdx.x;
    const int swz = (bid & 7) * 256 + (bid >> 3);   // flat row id: b*512 + y
    const int b   = swz >> 9;
    const int y   = swz & 511;
    const int x   = tid * 2;

    const float* __restrict__ logit_b = logit + (size_t)b * C_DIM * PLANE;

    // F loads first (deepest latency risk), pinned above the softmax work.
    const float* __restrict__ Fp = F + (size_t)b * 9 * PLANE + (size_t)y * W_DIM + x;
    float2 wk[9];
    #pragma unroll
    for (int k = 0; k < 9; ++k) wk[k] = *(const float2*)(Fp + (size_t)k * PLANE);
    __builtin_amdgcn_sched_barrier(0);   // don't sink F loads into the phases below

    build_E_nosync(matrix, E4, tid);
    __syncthreads();                     // E4 visible to all threads

    // ---- 3 softmax+encode passes (row y keeps its logit in registers) ----
    const int ym = max(y - 1, 0);
    const int yp = min(y + 1, H_DIM - 1);
    float2 lg[C_DIM];
    softmax2_to_lds(logit_b + (size_t)y  * W_DIM + x, E4, &ldsQ[1][x], lg);
    softmax2_to_lds(logit_b + (size_t)ym * W_DIM + x, E4, &ldsQ[0][x], nullptr);
    softmax2_to_lds(logit_b + (size_t)yp * W_DIM + x, E4, &ldsQ[2][x], nullptr);
    __syncthreads();

    // ---- 3x3 filter from LDS ----
    const bool vyr[3] = { y > 0, true, y < H_DIM - 1 };
    const int cols[4] = { max(x - 1, 0), x, x + 1, min(x + 2, W_DIM - 1) };
    const bool vxc[4] = { x > 0, true, true, x + 2 < W_DIM };

    float og[G_DIM][2];
    #pragma unroll
    for (int g = 0; g < G_DIM; ++g) { og[g][0] = 0.0f; og[g][1] = 0.0f; }

    #pragma unroll
    for (int r = 0; r < 3; ++r) {
        const uint4 q0 = ldsQ[r][cols[0]];
        const uint4 q1 = ldsQ[r][cols[1]];
        const uint4 q2 = ldsQ[r][cols[2]];
        const uint4 q3 = ldsQ[r][cols[3]];
        const uint4 qv_[4] = { q0, q1, q2, q3 };

        #pragma unroll
        for (int dxi = 0; dxi < 3; ++dxi) {
            const int k = r * 3 + dxi;
            const float wkv[2] = { wk[k].x, wk[k].y };
            #pragma unroll
            for (int j = 0; j < 2; ++j) {
                const bool v = vyr[r] & vxc[j + dxi];
                const float wv = v ? wkv[j] : 0.0f;
                const uint4 qv = qv_[j + dxi];
                og[0][j] = fmaf(wv, up_lo(qv.x), og[0][j]);
                og[1][j] = fmaf(wv, up_hi(qv.x), og[1][j]);
                og[2][j] = fmaf(wv, up_lo(qv.y), og[2][j]);
                og[3][j] = fmaf(wv, up_hi(qv.y), og[3][j]);
                og[4][j] = fmaf(wv, up_lo(qv.z), og[4][j]);
                og[5][j] = fmaf(wv, up_hi(qv.z), og[5][j]);
                og[6][j] = fmaf(wv, up_lo(qv.w), og[6][j]);
                og[7][j] = fmaf(wv, up_hi(qv.w), og[7][j]);
            }
        }
    }

    // ---- decode + subtract + nt-store (logit already in registers) ----
    float* __restrict__ op = out + (size_t)b * C_DIM * PLANE + (size_t)y * W_DIM + x;
    #pragma unroll
    for (int c = 0; c < C_DIM; ++c) {
        const float4 E0 = E4[c][0];
        const float4 E1 = E4[c][1];
        float d0 = og[0][0] * E0.x;
        float d1 = og[0][1] * E0.x;
        d0 = fmaf(og[1][0], E0.y, d0);  d1 = fmaf(og[1][1], E0.y, d1);
        d0 = fmaf(og[2][0], E0.z, d0);  d1 = fmaf(og[2][1], E0.z, d1);
        d0 = fmaf(og[3][0], E0.w, d0);  d1 = fmaf(og[3][1], E0.w, d1);
        d0 = fmaf(og[4][0], E1.x, d0);  d1 = fmaf(og[4][1], E1.x, d1);
        d0 = fmaf(og[5][0], E1.y, d0);  d1 = fmaf(og[5][1], E1.y, d1);
        d0 = fmaf(og[6][0], E1.z, d0);  d1 = fmaf(og[6][1], E1.z, d1);
        d0 = fmaf(og[7][0], E1.w, d0);  d1 = fmaf(og[7][1], E1.w, d1);
        ntstore2(op + (size_t)c * PLANE, lg[c].x - d0, lg[c].y - d1);
    }
}

extern "C" void kernel_launch(void* const* d_in, const int* in_sizes, int n_in,
                              void* d_out, int out_size, void* d_ws, size_t ws_size,
                              hipStream_t stream) {
    const float* F      = (const float*)d_in[0];   // [4, 9, 512, 512]
    const float* logit  = (const float*)d_in[1];   // [4, 19, 512, 512]
    const float* matrix = (const float*)d_in[2];   // [8, 19, 1, 1]
    float* out = (float*)d_out;                    // [4, 19, 512, 512]

    gacrf_row<<<B_DIM * H_DIM, NT, 0, stream>>>(F, logit, matrix, out);
}

// Round 15
// 47.136 us; speedup vs baseline: 1.4946x; 1.4946x over previous
//
#include <hip/hip_runtime.h>

#define C_DIM 19
#define G_DIM 8
#define H_DIM 512
#define W_DIM 512
#define B_DIM 4
#define PLANE (H_DIM * W_DIM)
#define NT    256
#define TLX   64
#define TLY   8
#define HXX   (TLX + 2)   // 66
#define HYY   (TLY + 2)   // 10

__device__ __forceinline__ unsigned bf16rne(float f) {
    unsigned x = __float_as_uint(f);
    return (x + 0x7fffu + ((x >> 16) & 1u)) >> 16;
}
__device__ __forceinline__ float up_lo(unsigned u) { return __uint_as_float(u << 16); }
__device__ __forceinline__ float up_hi(unsigned u) { return __uint_as_float(u & 0xffff0000u); }

// E = softmax(100*matrix over g): E4[c][0]=g0..3, E4[c][1]=g4..7.  NO sync inside.
__device__ __forceinline__ void build_E_nosync(const float* __restrict__ matrix,
                                               float4 (*E4)[2], int tid) {
    if (tid < C_DIM) {
        const int c = tid;
        float m[G_DIM];
        float mx = -1e30f;
        #pragma unroll
        for (int g = 0; g < G_DIM; ++g) {
            m[g] = 100.0f * matrix[g * C_DIM + c];
            mx = fmaxf(mx, m[g]);
        }
        float s = 0.0f;
        #pragma unroll
        for (int g = 0; g < G_DIM; ++g) { m[g] = __expf(m[g] - mx); s += m[g]; }
        const float inv = 1.0f / s;
        E4[c][0] = make_float4(m[0]*inv, m[1]*inv, m[2]*inv, m[3]*inv);
        E4[c][1] = make_float4(m[4]*inv, m[5]*inv, m[6]*inv, m[7]*inv);
    }
}

// ---- fully fused tile kernel: 64x8 output tile, 66x10 halo, 2048 blocks ----
__global__ __launch_bounds__(NT)
void gacrf_tile(const float* __restrict__ F,
                const float* __restrict__ logit,
                const float* __restrict__ matrix,
                float* __restrict__ out)
{
    __shared__ float4 E4[C_DIM][2];
    __shared__ uint4  ldsQ[HYY][HXX];   // 10560 B

    const int tid = threadIdx.x;

    // XCD-chunked bijective swizzle (2048 blocks, chunk 256): y-adjacent tiles
    // share an XCD L2 -> halo logit re-reads are L2-hits.
    const int bid = blockIdx.x;
    const int swz = (bid & 7) * 256 + (bid >> 3);
    const int b   = swz >> 9;
    const int rem = swz & 511;
    const int tby = rem >> 3;          // 0..63
    const int tbx = rem & 7;           // 0..7
    const int x0  = tbx * TLX;
    const int y0  = tby * TLY;

    const int tx = tid & 31;           // 0..31 (2 px each)
    const int ty = tid >> 5;           // 0..7
    const int gx = x0 + tx * 2;
    const int gy = y0 + ty;
    const size_t pix = (size_t)gy * W_DIM + gx;

    const float* __restrict__ logit_b = logit + (size_t)b * C_DIM * PLANE;

    // F loads issued early; latency hides under softmax phases
    const float* __restrict__ Fp = F + (size_t)b * 9 * PLANE + pix;
    float2 wk[9];
    #pragma unroll
    for (int k = 0; k < 9; ++k) wk[k] = *(const float2*)(Fp + (size_t)k * PLANE);

    build_E_nosync(matrix, E4, tid);
    __syncthreads();                   // E4 ready

    // ---- phase A: interior softmax+encode, 2 px/thread; keep logit in regs ----
    float2 lg[C_DIM];
    {
        const float* __restrict__ p = logit_b + pix;
        float eg[G_DIM][2];
        #pragma unroll
        for (int g = 0; g < G_DIM; ++g) { eg[g][0] = 0.0f; eg[g][1] = 0.0f; }
        float s0 = 0.0f, s1 = 0.0f;
        #pragma unroll
        for (int c = 0; c < C_DIM; ++c) {
            const float2 lv = *(const float2*)(p + (size_t)c * PLANE);
            lg[c] = lv;
            const float e0 = __expf(lv.x);
            const float e1 = __expf(lv.y);
            s0 += e0; s1 += e1;
            const float4 E0 = E4[c][0];
            const float4 E1 = E4[c][1];
            eg[0][0] = fmaf(E0.x, e0, eg[0][0]);  eg[0][1] = fmaf(E0.x, e1, eg[0][1]);
            eg[1][0] = fmaf(E0.y, e0, eg[1][0]);  eg[1][1] = fmaf(E0.y, e1, eg[1][1]);
            eg[2][0] = fmaf(E0.z, e0, eg[2][0]);  eg[2][1] = fmaf(E0.z, e1, eg[2][1]);
            eg[3][0] = fmaf(E0.w, e0, eg[3][0]);  eg[3][1] = fmaf(E0.w, e1, eg[3][1]);
            eg[4][0] = fmaf(E1.x, e0, eg[4][0]);  eg[4][1] = fmaf(E1.x, e1, eg[4][1]);
            eg[5][0] = fmaf(E1.y, e0, eg[5][0]);  eg[5][1] = fmaf(E1.y, e1, eg[5][1]);
            eg[6][0] = fmaf(E1.z, e0, eg[6][0]);  eg[6][1] = fmaf(E1.z, e1, eg[6][1]);
            eg[7][0] = fmaf(E1.w, e0, eg[7][0]);  eg[7][1] = fmaf(E1.w, e1, eg[7][1]);
        }
        const float i0 = 1.0f / s0;
        const float i1 = 1.0f / s1;
        uint4 u0, u1;
        u0.x = bf16rne(eg[0][0]*i0) | (bf16rne(eg[1][0]*i0) << 16);
        u0.y = bf16rne(eg[2][0]*i0) | (bf16rne(eg[3][0]*i0) << 16);
        u0.z = bf16rne(eg[4][0]*i0) | (bf16rne(eg[5][0]*i0) << 16);
        u0.w = bf16rne(eg[6][0]*i0) | (bf16rne(eg[7][0]*i0) << 16);
        u1.x = bf16rne(eg[0][1]*i1) | (bf16rne(eg[1][1]*i1) << 16);
        u1.y = bf16rne(eg[2][1]*i1) | (bf16rne(eg[3][1]*i1) << 16);
        u1.z = bf16rne(eg[4][1]*i1) | (bf16rne(eg[5][1]*i1) << 16);
        u1.w = bf16rne(eg[6][1]*i1) | (bf16rne(eg[7][1]*i1) << 16);
        ldsQ[1 + ty][1 + tx * 2]     = u0;
        ldsQ[1 + ty][1 + tx * 2 + 1] = u1;
    }

    // ---- phase B: halo ring, threads 0..147, 1 px each (parallel, short) ----
    if (tid < 148) {
        int hx, hy;
        if (tid < 66)       { hx = tid;        hy = 0; }
        else if (tid < 132) { hx = tid - 66;   hy = 9; }
        else if (tid < 140) { hx = 0;          hy = 1 + (tid - 132); }
        else                { hx = 65;         hy = 1 + (tid - 140); }
        const int hgx = min(max(x0 - 1 + hx, 0), W_DIM - 1);
        const int hgy = min(max(y0 - 1 + hy, 0), H_DIM - 1);
        const float* __restrict__ p = logit_b + (size_t)hgy * W_DIM + hgx;

        float eg[G_DIM];
        #pragma unroll
        for (int g = 0; g < G_DIM; ++g) eg[g] = 0.0f;
        float s = 0.0f;
        #pragma unroll
        for (int c = 0; c < C_DIM; ++c) {
            const float e = __expf(p[(size_t)c * PLANE]);
            s += e;
            const float4 E0 = E4[c][0];
            const float4 E1 = E4[c][1];
            eg[0] = fmaf(E0.x, e, eg[0]);
            eg[1] = fmaf(E0.y, e, eg[1]);
            eg[2] = fmaf(E0.z, e, eg[2]);
            eg[3] = fmaf(E0.w, e, eg[3]);
            eg[4] = fmaf(E1.x, e, eg[4]);
            eg[5] = fmaf(E1.y, e, eg[5]);
            eg[6] = fmaf(E1.z, e, eg[6]);
            eg[7] = fmaf(E1.w, e, eg[7]);
        }
        const float inv = 1.0f / s;
        uint4 u;
        u.x = bf16rne(eg[0]*inv) | (bf16rne(eg[1]*inv) << 16);
        u.y = bf16rne(eg[2]*inv) | (bf16rne(eg[3]*inv) << 16);
        u.z = bf16rne(eg[4]*inv) | (bf16rne(eg[5]*inv) << 16);
        u.w = bf16rne(eg[6]*inv) | (bf16rne(eg[7]*inv) << 16);
        ldsQ[hy][hx] = u;
    }
    __syncthreads();

    // ---- 3x3 filter from LDS (R7-proven) ----
    const bool vyr[3] = { gy > 0, true, gy < H_DIM - 1 };
    const bool vxc[4] = { gx > 0, true, true, gx + 2 < W_DIM };
    const int lx = tx * 2;             // LDS col of (gx-1)

    float og[G_DIM][2];
    #pragma unroll
    for (int g = 0; g < G_DIM; ++g) { og[g][0] = 0.0f; og[g][1] = 0.0f; }

    #pragma unroll
    for (int r = 0; r < 3; ++r) {
        const uint4 q0 = ldsQ[ty + r][lx];
        const uint4 q1 = ldsQ[ty + r][lx + 1];
        const uint4 q2 = ldsQ[ty + r][lx + 2];
        const uint4 q3 = ldsQ[ty + r][lx + 3];
        const uint4 qv_[4] = { q0, q1, q2, q3 };

        #pragma unroll
        for (int dxi = 0; dxi < 3; ++dxi) {
            const int k = r * 3 + dxi;
            const float wkv[2] = { wk[k].x, wk[k].y };
            #pragma unroll
            for (int j = 0; j < 2; ++j) {
                const bool v = vyr[r] & vxc[j + dxi];
                const float wv = v ? wkv[j] : 0.0f;
                const uint4 qv = qv_[j + dxi];
                og[0][j] = fmaf(wv, up_lo(qv.x), og[0][j]);
                og[1][j] = fmaf(wv, up_hi(qv.x), og[1][j]);
                og[2][j] = fmaf(wv, up_lo(qv.y), og[2][j]);
                og[3][j] = fmaf(wv, up_hi(qv.y), og[3][j]);
                og[4][j] = fmaf(wv, up_lo(qv.z), og[4][j]);
                og[5][j] = fmaf(wv, up_hi(qv.z), og[5][j]);
                og[6][j] = fmaf(wv, up_lo(qv.w), og[6][j]);
                og[7][j] = fmaf(wv, up_hi(qv.w), og[7][j]);
            }
        }
    }

    // ---- decode + subtract + store (logit already in registers) ----
    float* __restrict__ op = out + (size_t)b * C_DIM * PLANE + pix;
    #pragma unroll
    for (int c = 0; c < C_DIM; ++c) {
        const float4 E0 = E4[c][0];
        const float4 E1 = E4[c][1];
        float d0 = og[0][0] * E0.x;
        float d1 = og[0][1] * E0.x;
        d0 = fmaf(og[1][0], E0.y, d0);  d1 = fmaf(og[1][1], E0.y, d1);
        d0 = fmaf(og[2][0], E0.z, d0);  d1 = fmaf(og[2][1], E0.z, d1);
        d0 = fmaf(og[3][0], E0.w, d0);  d1 = fmaf(og[3][1], E0.w, d1);
        d0 = fmaf(og[4][0], E1.x, d0);  d1 = fmaf(og[4][1], E1.x, d1);
        d0 = fmaf(og[5][0], E1.y, d0);  d1 = fmaf(og[5][1], E1.y, d1);
        d0 = fmaf(og[6][0], E1.z, d0);  d1 = fmaf(og[6][1], E1.z, d1);
        d0 = fmaf(og[7][0], E1.w, d0);  d1 = fmaf(og[7][1], E1.w, d1);
        float2 o;
        o.x = lg[c].x - d0;
        o.y = lg[c].y - d1;
        *(float2*)(op + (size_t)c * PLANE) = o;
    }
}

extern "C" void kernel_launch(void* const* d_in, const int* in_sizes, int n_in,
                              void* d_out, int out_size, void* d_ws, size_t ws_size,
                              hipStream_t stream) {
    const float* F      = (const float*)d_in[0];   // [4, 9, 512, 512]
    const float* logit  = (const float*)d_in[1];   // [4, 19, 512, 512]
    const float* matrix = (const float*)d_in[2];   // [8, 19, 1, 1]
    float* out = (float*)d_out;                    // [4, 19, 512, 512]

    gacrf_tile<<<2048, NT, 0, stream>>>(F, logit, matrix, out);
}